// Round 3
// baseline (3179.482 us; speedup 1.0000x reference)
//
#include <hip/hip_runtime.h>
#include <hip/hip_bf16.h>

// Problem constants
#define BATCH 4096
#define TSTEPS 80
#define VOCAB 10000
#define EDIM 100
#define EPAD 128        // EDIM zero-padded to MFMA K multiple
#define UDIM 1024

typedef _Float16 half8 __attribute__((ext_vector_type(8)));
typedef float float4v __attribute__((ext_vector_type(4)));

__device__ __forceinline__ float tanh_fast(float x) {
    // tanh(x) = 1 - 2/(exp(2x)+1); exp under/overflow saturates to +-1
    return 1.0f - 2.0f / (__expf(2.0f * x) + 1.0f);
}

// Transpose+convert Wh[k][n] f32 -> WhT[n][k] fp16
__global__ __launch_bounds__(256) void convert_wh(const float* __restrict__ Wh,
                                                  _Float16* __restrict__ WhT) {
    int idx = blockIdx.x * 256 + threadIdx.x;        // 0 .. 1M-1
    int k = idx >> 10, n = idx & 1023;
    WhT[n * UDIM + k] = (_Float16)Wh[idx];
}

// Transpose+convert+pad Wx[e][u] f32 -> WxT[u][k] fp16, k in [0,128)
__global__ __launch_bounds__(256) void convert_wx(const float* __restrict__ Wx,
                                                  _Float16* __restrict__ WxT) {
    int idx = blockIdx.x * 256 + threadIdx.x;        // 0 .. 1024*128-1
    int n = idx >> 7, k = idx & 127;
    WxT[idx] = (k < EDIM) ? (_Float16)Wx[k * UDIM + n] : (_Float16)0.0f;
}

// One-time embedding gather: xemb[t][m][0:128] = pad(emb[inputs[m][t]])
__global__ __launch_bounds__(256) void embed_gather(
        const int* __restrict__ inputs, const float* __restrict__ emb,
        _Float16* __restrict__ xemb) {
    int c = blockIdx.x * 256 + threadIdx.x;    // one 8-half chunk; 80*4096*16 total
    int kc = c & 15;
    int m  = (c >> 4) & 4095;
    int t  = c >> 16;
    int tok = inputs[m * TSTEPS + t];
    const float* src = emb + (size_t)tok * EDIM + kc * 8;
    half8 v;
    #pragma unroll
    for (int e = 0; e < 8; ++e) {
        int k = kc * 8 + e;
        v[e] = (k < EDIM) ? (_Float16)src[e] : (_Float16)0.0f;
    }
    *(half8*)&xemb[(size_t)c * 8] = v;
}

// One recurrence step: h_out = tanh( xemb_t @ WxT' + b + h_in @ WhT' )
// NO LDS, NO barriers: both operands are K-contiguous, so MFMA fragments are
// direct 16-B global loads (frag: row = lane&15, k = (lane>>4)*8..+8).
// Block = 4 waves (2x2) covering 128x128; wave tile 64x64 (acc 4x4 of 16x16).
// Grid (8, 32): bx in [0,8) == XCD id -> each XCD's 128-col WhT slice (288 KB)
// stays L2-resident; twin waves share A/B rows through L1.
// Software pipeline: 4 fragment buffer sets, prefetch distance 2 -> compiler
// emits fine-grained vmcnt(N), no barrier ever drains the queue.
__global__ __launch_bounds__(256, 1) void rnn_step(
        const _Float16* __restrict__ xt,    // xemb + t*B*EPAD: [BATCH][EPAD]
        const _Float16* __restrict__ WxT,   // [UDIM][EPAD]
        const _Float16* __restrict__ WhT,   // [UDIM][UDIM]
        const float* __restrict__ bias,     // [UDIM]
        const _Float16* __restrict__ h_in,  // [BATCH][UDIM]
        _Float16* __restrict__ h_out)       // [BATCH][UDIM]
{
    const int tid  = threadIdx.x;
    const int lane = tid & 63;
    const int wave = tid >> 6;
    const int wm = (wave >> 1) * 64;
    const int wn = (wave & 1) * 64;
    const int m0 = blockIdx.y * 128;
    const int n0 = blockIdx.x * 128;
    const int lrow = lane & 15;
    const int lq   = lane >> 4;

    // Per-fragment-row base pointers (k-offset folded into load immediate)
    const _Float16 *ax[4], *ah[4], *bx[4], *bh[4];
    #pragma unroll
    for (int i = 0; i < 4; ++i) {
        const int ra = m0 + wm + i * 16 + lrow;   // A rows (batch)
        const int rb = n0 + wn + i * 16 + lrow;   // B rows (units)
        ax[i] = xt   + (size_t)ra * EPAD + lq * 8;
        ah[i] = h_in + (size_t)ra * UDIM + lq * 8;
        bx[i] = WxT  + (size_t)rb * EPAD + lq * 8;
        bh[i] = WhT  + (size_t)rb * UDIM + lq * 8;
    }

    float4v acc[4][4] = {};
    half8 a0[4], b0[4], a1[4], b1[4], a2[4], b2[4], a3[4], b3[4];

#define LDX(k, A, B) { _Pragma("unroll") \
    for (int i = 0; i < 4; ++i) { \
        A[i] = *(const half8*)(ax[i] + (k) * 32); \
        B[i] = *(const half8*)(bx[i] + (k) * 32); } }
#define LDH(k, A, B) { _Pragma("unroll") \
    for (int i = 0; i < 4; ++i) { \
        A[i] = *(const half8*)(ah[i] + (k) * 32); \
        B[i] = *(const half8*)(bh[i] + (k) * 32); } }
#define FMA(A, B) { _Pragma("unroll") \
    for (int i = 0; i < 4; ++i) { _Pragma("unroll") \
        for (int j = 0; j < 4; ++j) \
            acc[i][j] = __builtin_amdgcn_mfma_f32_16x16x32_f16(A[i], B[j], acc[i][j], 0, 0, 0); } }

    // x-segment (K=128, 4 iters) pipelined into h-segment (K=1024, 32 iters)
    LDX(0, a0, b0); LDX(1, a1, b1);
    LDX(2, a2, b2); FMA(a0, b0);
    LDX(3, a3, b3); FMA(a1, b1);
    LDH(0, a0, b0); FMA(a2, b2);
    LDH(1, a1, b1); FMA(a3, b3);

    #pragma unroll 1
    for (int kk = 0; kk <= 24; kk += 4) {     // 7 iters: FMA h0..h27
        LDH(kk + 2, a2, b2); FMA(a0, b0);
        LDH(kk + 3, a3, b3); FMA(a1, b1);
        LDH(kk + 4, a0, b0); FMA(a2, b2);
        LDH(kk + 5, a1, b1); FMA(a3, b3);
    }
    // tail: f0=h28, f1=h29
    LDH(30, a2, b2); FMA(a0, b0);
    LDH(31, a3, b3); FMA(a1, b1);
    FMA(a2, b2);
    FMA(a3, b3);
#undef LDX
#undef LDH
#undef FMA

    // Epilogue: bias + tanh, direct fp16 stores (32-B segments per 16 lanes)
    float bj[4];
    #pragma unroll
    for (int j = 0; j < 4; ++j)
        bj[j] = bias[n0 + wn + j * 16 + lrow];
    #pragma unroll
    for (int i = 0; i < 4; ++i) {
        #pragma unroll
        for (int j = 0; j < 4; ++j) {
            const int col = n0 + wn + j * 16 + lrow;
            #pragma unroll
            for (int r = 0; r < 4; ++r) {
                const int row = m0 + wm + i * 16 + lq * 4 + r;
                h_out[(size_t)row * UDIM + col] = (_Float16)tanh_fast(acc[i][j][r] + bj[j]);
            }
        }
    }
}

// out[b] = h[b,:] . Wo + bo   (one wave per row)
__global__ __launch_bounds__(256) void out_proj(const _Float16* __restrict__ h,
                                                const float* __restrict__ Wo,
                                                const float* __restrict__ bo,
                                                float* __restrict__ out) {
    const int lane = threadIdx.x & 63;
    const int wave = threadIdx.x >> 6;
    const int row = blockIdx.x * 4 + wave;
    const _Float16* hr = h + (size_t)row * UDIM;
    float s = 0.0f;
    #pragma unroll
    for (int i = 0; i < 16; ++i) {
        const int k = lane + i * 64;
        s += (float)hr[k] * Wo[k];
    }
    #pragma unroll
    for (int off = 32; off > 0; off >>= 1) s += __shfl_down(s, off, 64);
    if (lane == 0) out[row] = s + bo[0];
}

extern "C" void kernel_launch(void* const* d_in, const int* in_sizes, int n_in,
                              void* d_out, int out_size, void* d_ws, size_t ws_size,
                              hipStream_t stream) {
    const int*   inputs = (const int*)  d_in[0];   // [B,T]
    const float* emb    = (const float*)d_in[1];   // [V,E]
    const float* Wx     = (const float*)d_in[2];   // [E,U]
    const float* Wh     = (const float*)d_in[3];   // [U,U]
    const float* b      = (const float*)d_in[4];   // [U]
    const float* Wo     = (const float*)d_in[5];   // [U,1]
    const float* bo     = (const float*)d_in[6];   // [1]
    float* out = (float*)d_out;

    char* ws = (char*)d_ws;
    _Float16* WhT  = (_Float16*)ws;                                // 2 MB
    _Float16* WxT  = (_Float16*)(ws + (2u << 20));                 // 256 KB
    _Float16* hA   = (_Float16*)(ws + (2u << 20) + (256u << 10));  // 8 MB
    _Float16* hB   = hA + (size_t)BATCH * UDIM;                    // 8 MB
    _Float16* xemb = hB + (size_t)BATCH * UDIM;                    // 84 MB

    convert_wh<<<dim3(4096), dim3(256), 0, stream>>>(Wh, WhT);
    convert_wx<<<dim3(512),  dim3(256), 0, stream>>>(Wx, WxT);
    embed_gather<<<dim3(20480), dim3(256), 0, stream>>>(inputs, emb, xemb);
    hipMemsetAsync(hA, 0, (size_t)BATCH * UDIM * sizeof(_Float16), stream);

    for (int t = 0; t < TSTEPS; ++t) {
        const _Float16* hin  = (t & 1) ? hB : hA;
        _Float16*       hout = (t & 1) ? hA : hB;
        rnn_step<<<dim3(8, 32), dim3(256), 0, stream>>>(
            xemb + (size_t)t * BATCH * EPAD, WxT, WhT, b, hin, hout);
    }
    // T=80 even -> final h in hA
    out_proj<<<dim3(1024), dim3(256), 0, stream>>>(hA, Wo, bo, out);
}

// Round 4
// 2120.545 us; speedup vs baseline: 1.4994x; 1.4994x over previous
//
#include <hip/hip_runtime.h>
#include <hip/hip_bf16.h>

#define BATCH 4096
#define TSTEPS 80
#define VOCAB 10000
#define EDIM 100
#define UDIM 1024

typedef _Float16 half8 __attribute__((ext_vector_type(8)));
typedef float float4v __attribute__((ext_vector_type(4)));

// Fragment-major layout everywhere: chunk(blk, kblk, lane) holds
// M/N-row = blk*16 + (lane&15), k = kblk*32 + (lane>>4)*8 .. +8  (8 fp16 = 16 B).
// One fragment load = base + lane*16B -> fully coalesced 1 KB per wave inst.

__device__ __forceinline__ float tanh_fast(float x) {
    // tanh(x) = 1 - 2/(exp(2x)+1); exp under/overflow saturates to +-1
    return 1.0f - 2.0f / (__expf(2.0f * x) + 1.0f);
}

// Wh[k][n] f32 -> frag-major Wf: chunks [nblk(64)][kblk(32)][lane(64)][8]
__global__ __launch_bounds__(256) void convert_wh_frag(const float* __restrict__ Wh,
                                                       _Float16* __restrict__ Wf) {
    int cid = blockIdx.x * 256 + threadIdx.x;      // 0 .. 131071
    int lane = cid & 63, kblk = (cid >> 6) & 31, nblk = cid >> 11;
    int n = nblk * 16 + (lane & 15);
    int kb = kblk * 32 + (lane >> 4) * 8;
    half8 v;
    #pragma unroll
    for (int e = 0; e < 8; ++e) v[e] = (_Float16)Wh[(kb + e) * UDIM + n];
    *((half8*)Wf + cid) = v;
}

// Wx[e][u] f32 -> frag-major Wxf: chunks [nblk(64)][kblk(4)][lane][8], zero-padded k>=100
__global__ __launch_bounds__(256) void convert_wx_frag(const float* __restrict__ Wx,
                                                       _Float16* __restrict__ Wxf) {
    int cid = blockIdx.x * 256 + threadIdx.x;      // 0 .. 16383
    int lane = cid & 63, kblk = (cid >> 6) & 3, nblk = cid >> 8;
    int n = nblk * 16 + (lane & 15);
    int kb = kblk * 32 + (lane >> 4) * 8;
    half8 v;
    #pragma unroll
    for (int e = 0; e < 8; ++e)
        v[e] = (kb + e < EDIM) ? (_Float16)Wx[(kb + e) * UDIM + n] : (_Float16)0.0f;
    *((half8*)Wxf + cid) = v;
}

// emb gather -> frag-major xe: chunks [t(80)][mblk(256)][kblk(4)][lane][8]
__global__ __launch_bounds__(256) void embed_gather_frag(
        const int* __restrict__ inputs, const float* __restrict__ emb,
        _Float16* __restrict__ xe) {
    int cid = blockIdx.x * 256 + threadIdx.x;      // 0 .. 5242879
    int lane = cid & 63, kblk = (cid >> 6) & 3, mblk = (cid >> 8) & 255, t = cid >> 16;
    int m = mblk * 16 + (lane & 15);
    int kb = kblk * 32 + (lane >> 4) * 8;
    int tok = inputs[m * TSTEPS + t];
    const float* src = emb + (size_t)tok * EDIM;
    half8 v;
    #pragma unroll
    for (int e = 0; e < 8; ++e)
        v[e] = (kb + e < EDIM) ? (_Float16)src[kb + e] : (_Float16)0.0f;
    *((half8*)xe + cid) = v;
}

// xw_out (C-frag-packed f32) = xemb_t @ Wx + bias.  Geometry identical to rnn_step:
// block = 128x128 tile (mt = bid&31, nt = bid>>5), 4 waves of 64x64.
__device__ __forceinline__ void x_phase(
        const half8* __restrict__ xeT, const half8* __restrict__ Wxf,
        const float* __restrict__ bias, float4v* __restrict__ xw_out,
        int bid, int wave, int lane)
{
    const int mt = bid & 31, nt = bid >> 5;
    const int wmq = (wave >> 1) * 4, wnq = (wave & 1) * 4;
    const int lrow = lane & 15;
    const half8* pa[4]; const half8* pb[4];
    #pragma unroll
    for (int i = 0; i < 4; ++i) pa[i] = xeT + (size_t)(mt * 8 + wmq + i) * 4 * 64 + lane;
    #pragma unroll
    for (int j = 0; j < 4; ++j) pb[j] = Wxf + (size_t)(nt * 8 + wnq + j) * 4 * 64 + lane;
    float4v acc[4][4] = {};
    #pragma unroll
    for (int kb = 0; kb < 4; ++kb) {
        half8 a[4], b[4];
        #pragma unroll
        for (int i = 0; i < 4; ++i) a[i] = pa[i][kb * 64];
        #pragma unroll
        for (int j = 0; j < 4; ++j) b[j] = pb[j][kb * 64];
        #pragma unroll
        for (int i = 0; i < 4; ++i)
            #pragma unroll
            for (int j = 0; j < 4; ++j)
                acc[i][j] = __builtin_amdgcn_mfma_f32_16x16x32_f16(a[i], b[j], acc[i][j], 0, 0, 0);
    }
    #pragma unroll
    for (int j = 0; j < 4; ++j) {
        const float bj = bias[nt * 128 + (wave & 1) * 64 + j * 16 + lrow];
        #pragma unroll
        for (int i = 0; i < 4; ++i) {
            float4v v = acc[i][j] + bj;
            xw_out[((size_t)(bid * 4 + wave) * 16 + i * 4 + j) * 64 + lane] = v;
        }
    }
}

// h_out = tanh( xw_t + h_in @ Wh ), all operands frag-major; also emits xw_{t+1}.
// No __syncthreads anywhere: loop is pure register pipeline (D=2), epilogue
// transpose uses wave-private LDS (lgkmcnt deps only).
__global__ __launch_bounds__(256, 1) void rnn_step(
        const _Float16* __restrict__ h_in,   // frag-major [mblk 256][kblk 32][lane][8]
        const _Float16* __restrict__ Wf,     // frag-major [nblk 64][kblk 32][lane][8]
        const float4v* __restrict__ xw_cur,  // C-frag-packed [bid][wave][16][lane]
        _Float16* __restrict__ h_out,        // frag-major
        const _Float16* __restrict__ xe_next,// frag chunks for step t+1
        const _Float16* __restrict__ Wxf,
        const float* __restrict__ bias,
        float4v* __restrict__ xw_next,
        int do_x)
{
    __shared__ __align__(16) _Float16 tb[4][8][16 * 40];  // [wave][unit][16 rows x 40-half stride]

    const int tid = threadIdx.x;
    const int lane = tid & 63, wave = tid >> 6;
    const int bid = blockIdx.x;
    const int mt = bid & 31, nt = bid >> 5;   // XCD ~ bid%8 = mt%8 -> m-affinity
    const int wmq = (wave >> 1) * 4, wnq = (wave & 1) * 4;
    const int lrow = lane & 15, lq = lane >> 4;

    const half8* pa[4]; const half8* pb[4];
    #pragma unroll
    for (int i = 0; i < 4; ++i)
        pa[i] = (const half8*)h_in + (size_t)(mt * 8 + wmq + i) * 32 * 64 + lane;
    #pragma unroll
    for (int j = 0; j < 4; ++j)
        pb[j] = (const half8*)Wf + (size_t)(nt * 8 + wnq + j) * 32 * 64 + lane;

    float4v acc[4][4] = {};
    half8 a0[4], b0[4], a1[4], b1[4], a2[4], b2[4], a3[4], b3[4];

#define LD(kb, A, B) { _Pragma("unroll") \
    for (int i = 0; i < 4; ++i) { A[i] = pa[i][(kb) * 64]; B[i] = pb[i][(kb) * 64]; } }
#define FMA(A, B) { _Pragma("unroll") \
    for (int i = 0; i < 4; ++i) { _Pragma("unroll") \
        for (int j = 0; j < 4; ++j) \
            acc[i][j] = __builtin_amdgcn_mfma_f32_16x16x32_f16(A[i], B[j], acc[i][j], 0, 0, 0); } }

    LD(0, a0, b0); LD(1, a1, b1);
    LD(2, a2, b2); FMA(a0, b0);
    LD(3, a3, b3); FMA(a1, b1);
    #pragma unroll
    for (int i = 0; i < 4; ++i) { pa[i] += 256; pb[i] += 256; }

    #pragma unroll 1
    for (int g = 1; g < 8; ++g) {     // kb = 4g .. 4g+3
        LD(0, a0, b0); FMA(a2, b2);
        LD(1, a1, b1); FMA(a3, b3);
        LD(2, a2, b2); FMA(a0, b0);
        LD(3, a3, b3); FMA(a1, b1);
        #pragma unroll
        for (int i = 0; i < 4; ++i) { pa[i] += 256; pb[i] += 256; }
    }
    FMA(a2, b2); FMA(a3, b3);
#undef LD
#undef FMA

    // ---- Epilogue: acc + xw -> tanh -> fp16; C-layout -> A-layout via wave-private LDS ----
    const float4v* xwf = xw_cur + (size_t)(bid * 4 + wave) * 16 * 64 + lane;
    #pragma unroll
    for (int i = 0; i < 4; ++i) {
        #pragma unroll
        for (int j = 0; j < 4; ++j) {
            float4v w = xwf[(i * 4 + j) * 64];
            #pragma unroll
            for (int r = 0; r < 4; ++r) {
                // C-frag: row_local16 = lq*4+r, col_local16 = lrow; unit = (i, j>>1)
                tb[wave][i * 2 + (j >> 1)][(lq * 4 + r) * 40 + (j & 1) * 16 + lrow] =
                    (_Float16)tanh_fast(acc[i][j][r] + w[r]);
            }
        }
    }
    // same-wave LDS RAW: compiler inserts lgkmcnt waits; no barrier needed
    #pragma unroll
    for (int i = 0; i < 4; ++i) {
        #pragma unroll
        for (int jp = 0; jp < 2; ++jp) {
            half8 v = *(const half8*)&tb[wave][i * 2 + jp][(lane & 15) * 40 + lq * 8];
            const int mblk = mt * 8 + wmq + i;
            const int kblk = nt * 4 + (wave & 1) * 2 + jp;
            *((half8*)h_out + (size_t)(mblk * 32 + kblk) * 64 + lane) = v;
        }
    }

    if (do_x)
        x_phase((const half8*)xe_next, (const half8*)Wxf, bias, xw_next, bid, wave, lane);
}

// Bootstrap: xw_0
__global__ __launch_bounds__(256) void x_only(
        const _Float16* __restrict__ xeT, const _Float16* __restrict__ Wxf,
        const float* __restrict__ bias, float4v* __restrict__ xw_out) {
    x_phase((const half8*)xeT, (const half8*)Wxf, bias, xw_out,
            blockIdx.x, threadIdx.x >> 6, threadIdx.x & 63);
}

// out[b] = h[b,:].Wo + bo, h in frag-major layout
__global__ __launch_bounds__(256) void out_proj(const _Float16* __restrict__ h,
                                                const float* __restrict__ Wo,
                                                const float* __restrict__ bo,
                                                float* __restrict__ out) {
    const int lane = threadIdx.x & 63;
    const int wave = threadIdx.x >> 6;
    const int row = blockIdx.x * 4 + wave;
    const int mblk = row >> 4, lb = row & 15;
    const half8* hf = (const half8*)h;
    float s = 0.0f;
    #pragma unroll
    for (int c = 0; c < 2; ++c) {
        const int kblk = lane >> 1;
        const int q = (lane & 1) * 2 + c;
        half8 v = hf[(size_t)(mblk * 32 + kblk) * 64 + lb + q * 16];
        const int k0 = kblk * 32 + q * 8;
        #pragma unroll
        for (int e = 0; e < 8; ++e) s += (float)v[e] * Wo[k0 + e];
    }
    #pragma unroll
    for (int off = 32; off > 0; off >>= 1) s += __shfl_down(s, off, 64);
    if (lane == 0) out[row] = s + bo[0];
}

extern "C" void kernel_launch(void* const* d_in, const int* in_sizes, int n_in,
                              void* d_out, int out_size, void* d_ws, size_t ws_size,
                              hipStream_t stream) {
    const int*   inputs = (const int*)  d_in[0];   // [B,T]
    const float* emb    = (const float*)d_in[1];   // [V,E]
    const float* Wx     = (const float*)d_in[2];   // [E,U]
    const float* Wh     = (const float*)d_in[3];   // [U,U]
    const float* b      = (const float*)d_in[4];   // [U]
    const float* Wo     = (const float*)d_in[5];   // [U,1]
    const float* bo     = (const float*)d_in[6];   // [1]
    float* out = (float*)d_out;

    char* ws = (char*)d_ws;
    _Float16* Wf   = (_Float16*)ws;                          // 2 MB
    _Float16* Wxf  = (_Float16*)(ws + (2u  << 20));          // 256 KB
    _Float16* hA   = (_Float16*)(ws + (3u  << 20));          // 8 MB
    _Float16* hB   = (_Float16*)(ws + (11u << 20));          // 8 MB
    float4v*  xwA  = (float4v*) (ws + (19u << 20));          // 16 MB
    float4v*  xwB  = (float4v*) (ws + (35u << 20));          // 16 MB
    _Float16* xe   = (_Float16*)(ws + (51u << 20));          // 84 MB

    convert_wh_frag<<<dim3(512),   dim3(256), 0, stream>>>(Wh, Wf);
    convert_wx_frag<<<dim3(64),    dim3(256), 0, stream>>>(Wx, Wxf);
    embed_gather_frag<<<dim3(20480), dim3(256), 0, stream>>>(inputs, emb, xe);
    hipMemsetAsync(hA, 0, (size_t)BATCH * UDIM * sizeof(_Float16), stream);
    x_only<<<dim3(256), dim3(256), 0, stream>>>(xe, Wxf, b, xwA);  // xw_0

    for (int t = 0; t < TSTEPS; ++t) {
        const _Float16* hin  = (t & 1) ? hB : hA;
        _Float16*       hout = (t & 1) ? hA : hB;
        const float4v*  xwc  = (t & 1) ? xwB : xwA;
        float4v*        xwn  = (t & 1) ? xwA : xwB;
        const _Float16* xen  = xe + (size_t)(t + 1) * 65536 * 8;
        rnn_step<<<dim3(256), dim3(256), 0, stream>>>(
            hin, Wf, xwc, hout, xen, Wxf, b, xwn, t < TSTEPS - 1 ? 1 : 0);
    }
    // T=80 even -> final h in hA
    out_proj<<<dim3(1024), dim3(256), 0, stream>>>(hA, Wo, bo, out);
}

// Round 5
// 1659.941 us; speedup vs baseline: 1.9154x; 1.2775x over previous
//
#include <hip/hip_runtime.h>
#include <hip/hip_bf16.h>

#define BATCH 4096
#define TSTEPS 80
#define VOCAB 10000
#define EDIM 100
#define UDIM 1024

typedef _Float16 half8 __attribute__((ext_vector_type(8)));
typedef float float4v __attribute__((ext_vector_type(4)));

// Frag-major layout: chunk(blk, kblk, lane) = 16 B holding
// row = blk*16 + (lane&15), k = kblk*32 + (lane>>4)*8 .. +8.
// h:  [mblk 256][kblk 32][lane 64] chunks   Wf:  [nblk 64][kblk 32][lane]
// xe: [t][mblk 256][kblk 4][lane]           Wxf: [nblk 64][kblk 4][lane]

__device__ __forceinline__ void load_lds16(const void* g, void* l) {
    __builtin_amdgcn_global_load_lds(
        (const __attribute__((address_space(1))) unsigned int*)g,
        (__attribute__((address_space(3))) unsigned int*)l,
        16, 0, 0);
}

__device__ __forceinline__ float tanh_fast(float x) {
    return 1.0f - 2.0f / (__expf(2.0f * x) + 1.0f);
}

__global__ __launch_bounds__(256) void convert_wh_frag(const float* __restrict__ Wh,
                                                       _Float16* __restrict__ Wf) {
    int cid = blockIdx.x * 256 + threadIdx.x;      // 0 .. 131071
    int lane = cid & 63, kblk = (cid >> 6) & 31, nblk = cid >> 11;
    int n = nblk * 16 + (lane & 15);
    int kb = kblk * 32 + (lane >> 4) * 8;
    half8 v;
    #pragma unroll
    for (int e = 0; e < 8; ++e) v[e] = (_Float16)Wh[(kb + e) * UDIM + n];
    *((half8*)Wf + cid) = v;
}

__global__ __launch_bounds__(256) void convert_wx_frag(const float* __restrict__ Wx,
                                                       _Float16* __restrict__ Wxf) {
    int cid = blockIdx.x * 256 + threadIdx.x;      // 0 .. 16383
    int lane = cid & 63, kblk = (cid >> 6) & 3, nblk = cid >> 8;
    int n = nblk * 16 + (lane & 15);
    int kb = kblk * 32 + (lane >> 4) * 8;
    half8 v;
    #pragma unroll
    for (int e = 0; e < 8; ++e)
        v[e] = (kb + e < EDIM) ? (_Float16)Wx[(kb + e) * UDIM + n] : (_Float16)0.0f;
    *((half8*)Wxf + cid) = v;
}

__global__ __launch_bounds__(256) void embed_gather_frag(
        const int* __restrict__ inputs, const float* __restrict__ emb,
        _Float16* __restrict__ xe) {
    int cid = blockIdx.x * 256 + threadIdx.x;      // 0 .. 5242879
    int lane = cid & 63, kblk = (cid >> 6) & 3, mblk = (cid >> 8) & 255, t = cid >> 16;
    int m = mblk * 16 + (lane & 15);
    int kb = kblk * 32 + (lane >> 4) * 8;
    int tok = inputs[m * TSTEPS + t];
    const float* src = emb + (size_t)tok * EDIM;
    half8 v;
    #pragma unroll
    for (int e = 0; e < 8; ++e)
        v[e] = (kb + e < EDIM) ? (_Float16)src[kb + e] : (_Float16)0.0f;
    *((half8*)xe + cid) = v;
}

// h_out = tanh( xe_t @ Wx + b + h_in @ Wh )
// 128x128 tile, grid 256 (1 block/CU), mt = bid&31 -> XCD = bid%8 = mt%8.
// Fused K = 128 (x) + 1024 (h) = 18 iters of BK=64. Double-buffered LDS
// (64 KB), global_load_lds 16B, frag-major => linear stage + conflict-free
// lane*16B LDS fragment reads.
__global__ __launch_bounds__(256, 1) void rnn_step(
        const _Float16* __restrict__ h_in,
        const _Float16* __restrict__ xe_t,
        const _Float16* __restrict__ Wf,
        const _Float16* __restrict__ Wxf,
        const float* __restrict__ bias,
        _Float16* __restrict__ h_out)
{
    __shared__ __align__(16) _Float16 smem[32768];  // 64 KB = 2 buf x (A 16K + B 16K bytes)

    const int tid  = threadIdx.x;
    const int lane = tid & 63, wave = tid >> 6;
    const int bid  = blockIdx.x;
    const int mt = bid & 31, nt = bid >> 5;
    const int wmq = (wave >> 1) * 4, wnq = (wave & 1) * 4;   // 16-row block offsets
    const int lrow = lane & 15, lq = lane >> 4;

    const half8* hsrc  = (const half8*)h_in;
    const half8* xsrc  = (const half8*)xe_t;
    const half8* wsrc  = (const half8*)Wf;
    const half8* wxsrc = (const half8*)Wxf;

    // stage K-iter kk (0..17) into buffer buf: pure chunk copy, frag-major
    auto stage = [&](int kk, int buf) {
        const half8 *As, *Bs; int kstr, k0;
        if (kk < 2) { As = xsrc; Bs = wxsrc; kstr = 4;  k0 = kk * 2; }
        else        { As = hsrc; Bs = wsrc;  kstr = 32; k0 = (kk - 2) * 2; }
        _Float16* base = smem + buf * 16384;
        #pragma unroll
        for (int r = 0; r < 4; ++r) {
            int s = r * 256 + tid;            // chunk slot 0..1023
            int i = s >> 7, ks = (s >> 6) & 1, ln = s & 63;
            load_lds16(As + ((size_t)(mt * 8 + i) * kstr + k0 + ks) * 64 + ln,
                       base + s * 8);
            load_lds16(Bs + ((size_t)(nt * 8 + i) * kstr + k0 + ks) * 64 + ln,
                       base + 8192 + s * 8);
        }
    };

    float4v acc[4][4] = {};

    stage(0, 0);
    __syncthreads();

    #pragma unroll 1
    for (int kk = 0; kk < 18; ++kk) {
        const int buf = kk & 1;
        if (kk + 1 < 18) stage(kk + 1, buf ^ 1);

        const _Float16* Ab = smem + buf * 16384;
        const _Float16* Bb = Ab + 8192;
        half8 af[2][4], bf[2][4];
        #pragma unroll
        for (int ks = 0; ks < 2; ++ks) {
            #pragma unroll
            for (int i = 0; i < 4; ++i)
                af[ks][i] = *(const half8*)&Ab[(((wmq + i) * 2 + ks) * 64 + lane) * 8];
            #pragma unroll
            for (int j = 0; j < 4; ++j)
                bf[ks][j] = *(const half8*)&Bb[(((wnq + j) * 2 + ks) * 64 + lane) * 8];
        }
        #pragma unroll
        for (int ks = 0; ks < 2; ++ks)
            #pragma unroll
            for (int i = 0; i < 4; ++i)
                #pragma unroll
                for (int j = 0; j < 4; ++j)
                    acc[i][j] = __builtin_amdgcn_mfma_f32_16x16x32_f16(
                        af[ks][i], bf[ks][j], acc[i][j], 0, 0, 0);
        __syncthreads();
    }

    // ---- Epilogue: bias + tanh; C-layout -> A-layout via wave-private LDS ----
    _Float16* tb = smem + wave * 5120;      // [8 units][16 rows][40-half stride]
    float bj[4];
    #pragma unroll
    for (int j = 0; j < 4; ++j)
        bj[j] = bias[nt * 128 + (wave & 1) * 64 + j * 16 + lrow];
    #pragma unroll
    for (int i = 0; i < 4; ++i)
        #pragma unroll
        for (int j = 0; j < 4; ++j)
            #pragma unroll
            for (int r = 0; r < 4; ++r)
                tb[(i * 2 + (j >> 1)) * 640 + (lq * 4 + r) * 40 + (j & 1) * 16 + lrow] =
                    (_Float16)tanh_fast(acc[i][j][r] + bj[j]);
    // same-wave LDS RAW -> lgkmcnt only, no barrier
    #pragma unroll
    for (int i = 0; i < 4; ++i)
        #pragma unroll
        for (int jp = 0; jp < 2; ++jp) {
            half8 v = *(const half8*)&tb[(i * 2 + jp) * 640 + lrow * 40 + lq * 8];
            const int mblk = mt * 8 + wmq + i;
            const int kblk = nt * 4 + (wave & 1) * 2 + jp;
            *((half8*)h_out + (size_t)(mblk * 32 + kblk) * 64 + lane) = v;
        }
}

// out[b] = h[b,:].Wo + bo, h frag-major
__global__ __launch_bounds__(256) void out_proj(const _Float16* __restrict__ h,
                                                const float* __restrict__ Wo,
                                                const float* __restrict__ bo,
                                                float* __restrict__ out) {
    const int lane = threadIdx.x & 63;
    const int wave = threadIdx.x >> 6;
    const int row = blockIdx.x * 4 + wave;
    const int mblk = row >> 4, lb = row & 15;
    const half8* hf = (const half8*)h;
    float s = 0.0f;
    #pragma unroll
    for (int c = 0; c < 2; ++c) {
        const int kblk = lane >> 1;
        const int q = (lane & 1) * 2 + c;
        half8 v = hf[(size_t)(mblk * 32 + kblk) * 64 + lb + q * 16];
        const int k0 = kblk * 32 + q * 8;
        #pragma unroll
        for (int e = 0; e < 8; ++e) s += (float)v[e] * Wo[k0 + e];
    }
    #pragma unroll
    for (int off = 32; off > 0; off >>= 1) s += __shfl_down(s, off, 64);
    if (lane == 0) out[row] = s + bo[0];
}

extern "C" void kernel_launch(void* const* d_in, const int* in_sizes, int n_in,
                              void* d_out, int out_size, void* d_ws, size_t ws_size,
                              hipStream_t stream) {
    const int*   inputs = (const int*)  d_in[0];
    const float* emb    = (const float*)d_in[1];
    const float* Wx     = (const float*)d_in[2];
    const float* Wh     = (const float*)d_in[3];
    const float* b      = (const float*)d_in[4];
    const float* Wo     = (const float*)d_in[5];
    const float* bo     = (const float*)d_in[6];
    float* out = (float*)d_out;

    char* ws = (char*)d_ws;
    _Float16* Wf   = (_Float16*)ws;                          // 2 MB
    _Float16* Wxf  = (_Float16*)(ws + (2u  << 20));          // 256 KB
    _Float16* hA   = (_Float16*)(ws + (3u  << 20));          // 8 MB
    _Float16* hB   = (_Float16*)(ws + (11u << 20));          // 8 MB
    _Float16* xe   = (_Float16*)(ws + (19u << 20));          // 84 MB

    convert_wh_frag<<<dim3(512),    dim3(256), 0, stream>>>(Wh, Wf);
    convert_wx_frag<<<dim3(64),     dim3(256), 0, stream>>>(Wx, Wxf);
    embed_gather_frag<<<dim3(20480), dim3(256), 0, stream>>>(inputs, emb, xe);
    hipMemsetAsync(hA, 0, (size_t)BATCH * UDIM * sizeof(_Float16), stream);

    for (int t = 0; t < TSTEPS; ++t) {
        const _Float16* hin  = (t & 1) ? hB : hA;
        _Float16*       hout = (t & 1) ? hA : hB;
        rnn_step<<<dim3(256), dim3(256), 0, stream>>>(
            hin, xe + (size_t)t * 65536 * 8, Wf, Wxf, b, hout);
    }
    // T=80 even -> final h in hA
    out_proj<<<dim3(1024), dim3(256), 0, stream>>>(hA, Wo, bo, out);
}

// Round 6
// 1450.213 us; speedup vs baseline: 2.1924x; 1.1446x over previous
//
#include <hip/hip_runtime.h>
#include <hip/hip_bf16.h>

#define BATCH 4096
#define TSTEPS 80
#define VOCAB 10000
#define EDIM 100
#define UDIM 1024

typedef _Float16 half8 __attribute__((ext_vector_type(8)));
typedef float float4v __attribute__((ext_vector_type(4)));

// Frag-major layout: chunk(blk, kblk, lane) = 16 B holding
// row = blk*16 + (lane&15), k = kblk*32 + (lane>>4)*8 .. +8.
// h:  [mblk 256][kblk 32][lane 64] chunks   Wf:  [nblk 64][kblk 32][lane]
// xe: [t][mblk 256][kblk 4][lane]           Wxf: [nblk 64][kblk 4][lane]

__device__ __forceinline__ void load_lds16(const void* g, void* l) {
    __builtin_amdgcn_global_load_lds(
        (const __attribute__((address_space(1))) unsigned int*)g,
        (__attribute__((address_space(3))) unsigned int*)l,
        16, 0, 0);
}

__device__ __forceinline__ float tanh_fast(float x) {
    return 1.0f - 2.0f / (__expf(2.0f * x) + 1.0f);
}

__global__ __launch_bounds__(256) void convert_wh_frag(const float* __restrict__ Wh,
                                                       _Float16* __restrict__ Wf) {
    int cid = blockIdx.x * 256 + threadIdx.x;      // 0 .. 131071
    int lane = cid & 63, kblk = (cid >> 6) & 31, nblk = cid >> 11;
    int n = nblk * 16 + (lane & 15);
    int kb = kblk * 32 + (lane >> 4) * 8;
    half8 v;
    #pragma unroll
    for (int e = 0; e < 8; ++e) v[e] = (_Float16)Wh[(kb + e) * UDIM + n];
    *((half8*)Wf + cid) = v;
}

__global__ __launch_bounds__(256) void convert_wx_frag(const float* __restrict__ Wx,
                                                       _Float16* __restrict__ Wxf) {
    int cid = blockIdx.x * 256 + threadIdx.x;      // 0 .. 16383
    int lane = cid & 63, kblk = (cid >> 6) & 3, nblk = cid >> 8;
    int n = nblk * 16 + (lane & 15);
    int kb = kblk * 32 + (lane >> 4) * 8;
    half8 v;
    #pragma unroll
    for (int e = 0; e < 8; ++e)
        v[e] = (kb + e < EDIM) ? (_Float16)Wx[(kb + e) * UDIM + n] : (_Float16)0.0f;
    *((half8*)Wxf + cid) = v;
}

__global__ __launch_bounds__(256) void embed_gather_frag(
        const int* __restrict__ inputs, const float* __restrict__ emb,
        _Float16* __restrict__ xe) {
    int cid = blockIdx.x * 256 + threadIdx.x;      // 0 .. 5242879
    int lane = cid & 63, kblk = (cid >> 6) & 3, mblk = (cid >> 8) & 255, t = cid >> 16;
    int m = mblk * 16 + (lane & 15);
    int kb = kblk * 32 + (lane >> 4) * 8;
    int tok = inputs[m * TSTEPS + t];
    const float* src = emb + (size_t)tok * EDIM;
    half8 v;
    #pragma unroll
    for (int e = 0; e < 8; ++e)
        v[e] = (kb + e < EDIM) ? (_Float16)src[kb + e] : (_Float16)0.0f;
    *((half8*)xe + cid) = v;
}

// h_out = tanh( xe_t @ Wx + b + h_in @ Wh )
// 128x128 tile, grid 256 (1 block/CU), mt = bid&31 -> XCD = bid%8 = mt%8.
// Fused K = 1152 as 9 iters of BK=128 (iter 0 = whole x-segment).
// Double-buffered 128 KB LDS (2 x (A 32K + B 32K)); frag-major => linear
// 16B-chunk staging (global_load_lds dwordx4) + conflict-free lane*16B reads.
__global__ __launch_bounds__(256, 1) void rnn_step(
        const _Float16* __restrict__ h_in,
        const _Float16* __restrict__ xe_t,
        const _Float16* __restrict__ Wf,
        const _Float16* __restrict__ Wxf,
        const float* __restrict__ bias,
        _Float16* __restrict__ h_out)
{
    __shared__ __align__(16) _Float16 smem[65536];  // 128 KB

    const int tid  = threadIdx.x;
    const int lane = tid & 63, wave = tid >> 6;
    const int bid  = blockIdx.x;
    const int mt = bid & 31, nt = bid >> 5;
    const int wmq = (wave >> 1) * 4, wnq = (wave & 1) * 4;   // 16-row block offsets
    const int lrow = lane & 15, lq = lane >> 4;

    const half8* hsrc  = (const half8*)h_in;
    const half8* xsrc  = (const half8*)xe_t;
    const half8* wsrc  = (const half8*)Wf;
    const half8* wxsrc = (const half8*)Wxf;

    // stage BK-128 slice kk (0..8) into buffer buf: pure linear chunk copy
    auto stage = [&](int kk, int buf) {
        const half8 *As, *Bs; int kstr, k0;
        if (kk == 0) { As = xsrc; Bs = wxsrc; kstr = 4;  k0 = 0; }
        else         { As = hsrc; Bs = wsrc;  kstr = 32; k0 = (kk - 1) * 4; }
        _Float16* base = smem + buf * 32768;
        #pragma unroll
        for (int r = 0; r < 8; ++r) {
            int s = r * 256 + tid;            // chunk slot 0..2047
            int i = s >> 8, ks = (s >> 6) & 3, ln = s & 63;
            load_lds16(As + ((size_t)(mt * 8 + i) * kstr + k0 + ks) * 64 + ln,
                       base + s * 8);
            load_lds16(Bs + ((size_t)(nt * 8 + i) * kstr + k0 + ks) * 64 + ln,
                       base + 16384 + s * 8);
        }
    };

    float4v acc[4][4] = {};

    stage(0, 0);
    __syncthreads();

    #pragma unroll 1
    for (int kk = 0; kk < 9; ++kk) {
        const int buf = kk & 1;
        if (kk + 1 < 9) stage(kk + 1, buf ^ 1);

        const _Float16* Ab = smem + buf * 32768;
        const _Float16* Bb = Ab + 16384;
        #pragma unroll
        for (int ks = 0; ks < 4; ++ks) {       // four K-32 slices
            half8 af[4], bf[4];
            #pragma unroll
            for (int i = 0; i < 4; ++i)
                af[i] = *(const half8*)&Ab[(((wmq + i) * 4 + ks) * 64 + lane) * 8];
            #pragma unroll
            for (int j = 0; j < 4; ++j)
                bf[j] = *(const half8*)&Bb[(((wnq + j) * 4 + ks) * 64 + lane) * 8];
            #pragma unroll
            for (int i = 0; i < 4; ++i)
                #pragma unroll
                for (int j = 0; j < 4; ++j)
                    acc[i][j] = __builtin_amdgcn_mfma_f32_16x16x32_f16(
                        af[i], bf[j], acc[i][j], 0, 0, 0);
        }
        __syncthreads();
    }

    // ---- Epilogue: bias + tanh; C-layout -> A-layout via wave-private LDS ----
    _Float16* tb = smem + wave * 5120;      // [8 units][16 rows][40-half stride]
    float bj[4];
    #pragma unroll
    for (int j = 0; j < 4; ++j)
        bj[j] = bias[nt * 128 + (wave & 1) * 64 + j * 16 + lrow];
    #pragma unroll
    for (int i = 0; i < 4; ++i)
        #pragma unroll
        for (int j = 0; j < 4; ++j)
            #pragma unroll
            for (int r = 0; r < 4; ++r)
                tb[(i * 2 + (j >> 1)) * 640 + (lq * 4 + r) * 40 + (j & 1) * 16 + lrow] =
                    (_Float16)tanh_fast(acc[i][j][r] + bj[j]);
    // same-wave LDS RAW -> lgkmcnt only, no barrier
    #pragma unroll
    for (int i = 0; i < 4; ++i)
        #pragma unroll
        for (int jp = 0; jp < 2; ++jp) {
            half8 v = *(const half8*)&tb[(i * 2 + jp) * 640 + lrow * 40 + lq * 8];
            const int mblk = mt * 8 + wmq + i;
            const int kblk = nt * 4 + (wave & 1) * 2 + jp;
            *((half8*)h_out + (size_t)(mblk * 32 + kblk) * 64 + lane) = v;
        }
}

// out[b] = h[b,:].Wo + bo, h frag-major
__global__ __launch_bounds__(256) void out_proj(const _Float16* __restrict__ h,
                                                const float* __restrict__ Wo,
                                                const float* __restrict__ bo,
                                                float* __restrict__ out) {
    const int lane = threadIdx.x & 63;
    const int wave = threadIdx.x >> 6;
    const int row = blockIdx.x * 4 + wave;
    const int mblk = row >> 4, lb = row & 15;
    const half8* hf = (const half8*)h;
    float s = 0.0f;
    #pragma unroll
    for (int c = 0; c < 2; ++c) {
        const int kblk = lane >> 1;
        const int q = (lane & 1) * 2 + c;
        half8 v = hf[(size_t)(mblk * 32 + kblk) * 64 + lb + q * 16];
        const int k0 = kblk * 32 + q * 8;
        #pragma unroll
        for (int e = 0; e < 8; ++e) s += (float)v[e] * Wo[k0 + e];
    }
    #pragma unroll
    for (int off = 32; off > 0; off >>= 1) s += __shfl_down(s, off, 64);
    if (lane == 0) out[row] = s + bo[0];
}

extern "C" void kernel_launch(void* const* d_in, const int* in_sizes, int n_in,
                              void* d_out, int out_size, void* d_ws, size_t ws_size,
                              hipStream_t stream) {
    const int*   inputs = (const int*)  d_in[0];
    const float* emb    = (const float*)d_in[1];
    const float* Wx     = (const float*)d_in[2];
    const float* Wh     = (const float*)d_in[3];
    const float* b      = (const float*)d_in[4];
    const float* Wo     = (const float*)d_in[5];
    const float* bo     = (const float*)d_in[6];
    float* out = (float*)d_out;

    char* ws = (char*)d_ws;
    _Float16* Wf   = (_Float16*)ws;                          // 2 MB
    _Float16* Wxf  = (_Float16*)(ws + (2u  << 20));          // 256 KB
    _Float16* hA   = (_Float16*)(ws + (3u  << 20));          // 8 MB
    _Float16* hB   = (_Float16*)(ws + (11u << 20));          // 8 MB
    _Float16* xe   = (_Float16*)(ws + (19u << 20));          // 84 MB

    convert_wh_frag<<<dim3(512),    dim3(256), 0, stream>>>(Wh, Wf);
    convert_wx_frag<<<dim3(64),     dim3(256), 0, stream>>>(Wx, Wxf);
    embed_gather_frag<<<dim3(20480), dim3(256), 0, stream>>>(inputs, emb, xe);
    hipMemsetAsync(hA, 0, (size_t)BATCH * UDIM * sizeof(_Float16), stream);

    for (int t = 0; t < TSTEPS; ++t) {
        const _Float16* hin  = (t & 1) ? hB : hA;
        _Float16*       hout = (t & 1) ? hA : hB;
        rnn_step<<<dim3(256), dim3(256), 0, stream>>>(
            hin, xe + (size_t)t * 65536 * 8, Wf, Wxf, b, hout);
    }
    // T=80 even -> final h in hA
    out_proj<<<dim3(1024), dim3(256), 0, stream>>>(hA, Wo, bo, out);
}